// Round 5
// baseline (5570.186 us; speedup 1.0000x reference)
//
#include <hip/hip_runtime.h>
#include <math.h>

// ---------------- fixed workspace layout (float offsets) ----------------
#define OFF_CWP  0L         // conv w  [l8][k9][ib4][wv16][i32][o8]   = 1179648
#define OFF_FWF  1179648L   // fus  w  [l8][wv16][ic8][i16][o16]      = 262144
#define OFF_W1G  1441792L   // W1G  [c256][o512]                      = 131072
#define OFF_W1S  1572864L   // W1S  [ob2][ch1024][o256]               = 524288
#define OFF_W2P  2097152L   // W2P  [c8][i32][j128]                   = 32768
#define OFF_GRAW 2129920L   // graw [512][256]                        = 131072
#define OFF_HG   2260992L   // hg   [512][512]                        = 262144
#define OFF_DYN  2523136L   // dynamic: states [C][1024][128] + h1 [C][512][128]
#define REPACK_N 2129920L

__global__ void k_repack(const float* __restrict__ head_w, const float* __restrict__ res_w,
                         const float* __restrict__ fusion_w,
                         const float* __restrict__ pred1_w, const float* __restrict__ cls1_w,
                         const float* __restrict__ pred2_w, const float* __restrict__ cls2_w,
                         float* __restrict__ ws) {
  long j = (long)blockIdx.x * 256 + threadIdx.x;
  if (j >= REPACK_N) return;
  if (j < OFF_FWF) {                       // CWP
    int o = (int)(j & 7), i = (int)((j >> 3) & 31), wv = (int)((j >> 8) & 15);
    int ib = (int)((j >> 12) & 3); long r = j >> 14; int k = (int)(r % 9), l = (int)(r / 9);
    int og = wv * 8 + o, ig = ib * 32 + i;
    float v;
    if (l == 0) v = (ig < 67) ? head_w[(og * 67 + ig) * 9 + k] : 0.f;
    else        v = res_w[(((l - 1) * 128 + og) * 128 + ig) * 9 + k];
    ws[j] = v;
  } else if (j < OFF_W1G) {                // FWF
    long q = j - OFF_FWF;
    int o = (int)(q & 15), i = (int)((q >> 4) & 15), ic = (int)((q >> 8) & 7);
    int wv = (int)((q >> 11) & 15), l = (int)(q >> 15);
    ws[j] = fusion_w[(long)(wv * 16 + o) * 1024 + l * 128 + ic * 16 + i];
  } else if (j < OFF_W1S) {                // W1G
    long q = j - OFF_W1G; int o = (int)(q & 511); int c = (int)(q >> 9);
    ws[j] = (o < 256) ? pred1_w[(long)o * 1280 + c] : cls1_w[(long)(o - 256) * 1280 + c];
  } else if (j < OFF_W2P) {                // W1S
    long q = j - OFF_W1S; int o = (int)(q & 255); int ch = (int)((q >> 8) & 1023); int ob = (int)(q >> 18);
    int c = 256 + ch;
    ws[j] = (ob == 0) ? pred1_w[(long)o * 1280 + c] : cls1_w[(long)o * 1280 + c];
  } else if (j < OFF_GRAW) {               // W2P
    long q = j - OFF_W2P; int jj = (int)(q & 127); int i = (int)((q >> 7) & 31); int c = (int)(q >> 12);
    ws[j] = (jj < 64) ? pred2_w[jj * 256 + c * 32 + i] : cls2_w[(jj - 64) * 256 + c * 32 + i];
  }
}

__device__ __forceinline__ void cp16(const float* g, float* l) {
  __builtin_amdgcn_global_load_lds((const __attribute__((address_space(1))) unsigned int*)g,
                                   (__attribute__((address_space(3))) unsigned int*)l, 16, 0, 0);
}

// =============== K1: gather + 8-layer conv chain + incremental fus + states write ===============
__global__ __launch_bounds__(1024) __attribute__((amdgpu_waves_per_eu(4, 4)))
void k_conv(const float* __restrict__ cnn, const float* __restrict__ i_it,
            const float* __restrict__ c_it, const float* __restrict__ cls_in,
            const int* __restrict__ ind,
            const float* __restrict__ CWP, const float* __restrict__ FWF,
            const float* __restrict__ head_b, const float* __restrict__ res_b,
            float* __restrict__ graw, float* __restrict__ states, int p0) {
  __shared__ float sx[16384];    // [128 ch][128 pos] 64 KB
  __shared__ float wbuf[8192];   // 16 waves x 2 x 256 floats, 32 KB
  const int ln = blockIdx.x, n = p0 + ln, t = threadIdx.x;
  const int po = t & 63;
  const int wv = __builtin_amdgcn_readfirstlane(t >> 6);
  float* wb = wbuf + wv * 512;
  const int ob = wv * 8;

  // ---- bilinear gather ----
  {
    const int p4 = t & 127, og4 = t >> 7;
    const float gx = i_it[((long)n * 128 + p4) * 2 + 0] - 0.5f;
    const float gy = i_it[((long)n * 128 + p4) * 2 + 1] - 0.5f;
    const float fx = floorf(gx), fy = floorf(gy);
    const float wx = gx - fx, wy = gy - fy;
    const int x0 = (int)fx, y0 = (int)fy, x1 = x0 + 1, y1 = y0 + 1;
    const bool vx0 = (x0 >= 0) & (x0 < 128), vx1 = (x1 >= 0) & (x1 < 128);
    const bool vy0 = (y0 >= 0) & (y0 < 128), vy1 = (y1 >= 0) & (y1 < 128);
    const int x0c = min(max(x0, 0), 127), x1c = min(max(x1, 0), 127);
    const int y0c = min(max(y0, 0), 127), y1c = min(max(y1, 0), 127);
    const float w00 = (vx0 && vy0) ? (1.f - wx) * (1.f - wy) : 0.f;
    const float w01 = (vx1 && vy0) ? wx * (1.f - wy) : 0.f;
    const float w10 = (vx0 && vy1) ? (1.f - wx) * wy : 0.f;
    const float w11 = (vx1 && vy1) ? wx * wy : 0.f;
    const long base = (long)ind[n] * 64 * 16384;
    const int a00 = y0c * 128 + x0c, a01 = y0c * 128 + x1c;
    const int a10 = y1c * 128 + x0c, a11 = y1c * 128 + x1c;
    for (int cc = 0; cc < 8; cc++) {
      const int c = og4 * 8 + cc;
      const float* f = cnn + base + (long)c * 16384;
      sx[c * 128 + p4] = f[a00] * w00 + f[a01] * w01 + f[a10] * w10 + f[a11] * w11;
    }
    if (og4 == 0) {
      sx[64 * 128 + p4] = c_it[((long)n * 128 + p4) * 2 + 0] * 4.0f;
      sx[65 * 128 + p4] = c_it[((long)n * 128 + p4) * 2 + 1] * 4.0f;
      sx[66 * 128 + p4] = cls_in[(long)n * 128 + p4];
    }
  }
  for (int idx = t; idx < 61 * 128; idx += 1024) sx[67 * 128 + idx] = 0.f;  // full zero-pad
  __syncthreads();

  float f0[16], f1[16];
#pragma unroll
  for (int r = 0; r < 16; r++) { f0[r] = 0.f; f1[r] = 0.f; }
  float* st = states + (long)ln * 131072;

  for (int l = 0; l < 8; l++) {
    const int dil = (l >= 6) ? 4 : ((l >= 4) ? 2 : 1);
    float a0[8], a1[8];
    {
      const float* bsrc = (l == 0) ? (head_b + ob) : (res_b + (l - 1) * 128 + ob);
#pragma unroll
      for (int oo = 0; oo < 8; oo++) { a0[oo] = bsrc[oo]; a1[oo] = a0[oo]; }
    }
    const float* wl = CWP + (long)l * 147456 + wv * 256;
    asm volatile("s_waitcnt vmcnt(0)" ::: "memory");   // drain bias/gather/prior stores
    cp16(wl + po * 4, wb);
    for (int c = 0; c < 36; c++) {
      if (c + 1 < 36) {
        cp16(wl + (long)(c + 1) * 4096 + po * 4, wb + ((c + 1) & 1) * 256);
        asm volatile("s_waitcnt vmcnt(1)" ::: "memory");
      } else {
        asm volatile("s_waitcnt vmcnt(0)" ::: "memory");
      }
      const int k = c >> 2, ib = c & 3;
      const int xa0 = (po + (k - 4) * dil + 128) & 127;
      const int xa1 = xa0 ^ 64;
      const float* w = wb + (c & 1) * 256;
      const float* xr = sx + ib * 32 * 128;
#pragma unroll 4
      for (int i = 0; i < 32; i++) {
        const float xv0 = xr[i * 128 + xa0];
        const float xv1 = xr[i * 128 + xa1];
        const float* wi = w + i * 8;
#pragma unroll
        for (int oo = 0; oo < 8; oo++) {
          a0[oo] = fmaf(wi[oo], xv0, a0[oo]);
          a1[oo] = fmaf(wi[oo], xv1, a1[oo]);
        }
      }
    }
    __syncthreads();
#pragma unroll
    for (int oo = 0; oo < 8; oo++) {
      const int o = ob + oo;
      float v0 = fmaxf(a0[oo], 0.f), v1 = fmaxf(a1[oo], 0.f);
      if (l > 0) { v0 += sx[o * 128 + po]; v1 += sx[o * 128 + po + 64]; }
      sx[o * 128 + po] = v0;
      sx[o * 128 + po + 64] = v1;
      st[(l * 128 + o) * 128 + po] = v0;        // states write (coalesced)
      st[(l * 128 + o) * 128 + po + 64] = v1;
    }
    asm volatile("s_waitcnt vmcnt(0)" ::: "memory");   // drain state stores before DMA discipline
    __syncthreads();

    // ---- incremental fusion accumulation for slot l ----
    const float* fl = FWF + ((long)l * 16 + wv) * 2048;
    cp16(fl + po * 4, wb);
    for (int ic = 0; ic < 8; ic++) {
      if (ic + 1 < 8) {
        cp16(fl + (long)(ic + 1) * 256 + po * 4, wb + ((ic + 1) & 1) * 256);
        asm volatile("s_waitcnt vmcnt(1)" ::: "memory");
      } else {
        asm volatile("s_waitcnt vmcnt(0)" ::: "memory");
      }
      const float* w = wb + (ic & 1) * 256;
#pragma unroll 4
      for (int i = 0; i < 16; i++) {
        const int ig = ic * 16 + i;
        const float xv0 = sx[ig * 128 + po];
        const float xv1 = sx[ig * 128 + po + 64];
        const float* wr = w + i * 16;
#pragma unroll
        for (int r = 0; r < 16; r++) {
          f0[r] = fmaf(wr[r], xv0, f0[r]);
          f1[r] = fmaf(wr[r], xv1, f1[r]);
        }
      }
    }
  }

  // ---- fusion max over all 128 positions -> graw ----
#pragma unroll
  for (int r = 0; r < 16; r++) {
    float m = fmaxf(f0[r], f1[r]);
#pragma unroll
    for (int s = 32; s > 0; s >>= 1) m = fmaxf(m, __shfl_xor(m, s, 64));
    if (po == 0) graw[(long)n * 256 + wv * 16 + r] = m;
  }
}

// =============== K_hg: hg[n][o] = bias + W1G[:,o].(graw+fus_b) ===============
__global__ __launch_bounds__(512)
void k_hg(const float* __restrict__ graw, const float* __restrict__ fus_b,
          const float* __restrict__ W1G, const float* __restrict__ p1b, const float* __restrict__ c1b,
          float* __restrict__ hg, int p0) {
  __shared__ float sg[256];
  const int n = p0 + blockIdx.x, t = threadIdx.x;
  if (t < 256) sg[t] = graw[(long)n * 256 + t] + fus_b[t];
  __syncthreads();
  float s = (t < 256) ? p1b[t] : c1b[t - 256];
  const float* w = W1G + t;
#pragma unroll 8
  for (int c = 0; c < 256; c++) s = fmaf(w[(long)c * 512], sg[c], s);
  hg[(long)n * 512 + t] = s;
}

// =============== K2h: h1 = relu(W1S @ states + hg), 2 blocks/poly ===============
__global__ __launch_bounds__(1024) __attribute__((amdgpu_waves_per_eu(4, 4)))
void k_h1(const float* __restrict__ states, const float* __restrict__ W1S,
          const float* __restrict__ hg, float* __restrict__ h1, int p0) {
  __shared__ float xb[2][2048];    // 16 ch x 128 pos, dbuf (16 KB)
  __shared__ float wbs[2][4096];   // 16 ch x 256 o,  dbuf (32 KB)
  const int b = blockIdx.x, ln = b >> 1, obh = b & 1;
  const int t = threadIdx.x, po = t & 63;
  const int wv = __builtin_amdgcn_readfirstlane(t >> 6);
  const int ss = wv >> 1, hf = wv & 1, p = hf * 64 + po;
  const float* xs = states + (long)ln * 131072;
  const float* wsrc = W1S + (long)obh * 262144;
  float acc[32];
#pragma unroll
  for (int oo = 0; oo < 32; oo++) acc[oo] = 0.f;

  float2 px = ((const float2*)xs)[t];
  float4 pw = ((const float4*)wsrc)[t];
  int buf = 0;
  for (int c = 0; c < 64; c++) {
    ((float2*)xb[buf])[t] = px;
    ((float4*)wbs[buf])[t] = pw;
    __syncthreads();
    if (c + 1 < 64) {
      px = ((const float2*)(xs + (long)(c + 1) * 2048))[t];
      pw = ((const float4*)(wsrc + (long)(c + 1) * 4096))[t];
    }
    const float* xp = xb[buf];
    const float* wp = wbs[buf] + ss * 32;
#pragma unroll 4
    for (int i = 0; i < 16; i++) {
      const float xv = xp[i * 128 + p];
      const float* w = wp + i * 256;
#pragma unroll
      for (int oo = 0; oo < 32; oo++) acc[oo] = fmaf(w[oo], xv, acc[oo]);
    }
    __syncthreads();
    buf ^= 1;
  }
  const int n = p0 + ln;
  const float* hgp = hg + (long)n * 512 + obh * 256 + ss * 32;
  float* dst = h1 + (long)ln * 65536 + (long)(obh * 256 + ss * 32) * 128 + p;
#pragma unroll
  for (int oo = 0; oo < 32; oo++) dst[oo * 128] = fmaxf(acc[oo] + hgp[oo], 0.f);
}

// =============== K3: pred2/cls2 + pred3/cls3 + outputs + NMS ===============
__global__ __launch_bounds__(1024) __attribute__((amdgpu_waves_per_eu(4, 4)))
void k_tail(const float* __restrict__ h1, const float* __restrict__ W2P,
            const float* __restrict__ p2b, const float* __restrict__ c2b,
            const float* __restrict__ p3w, const float* __restrict__ p3b,
            const float* __restrict__ c3w, const float* __restrict__ c3b,
            const float* __restrict__ i_it, float* __restrict__ out, int p0) {
  __shared__ float xbp[4096], xbc[4096], wb2[4096];   // 48 KB staging
  __shared__ float h2[16384];                          // 64 KB
  const int ln = blockIdx.x, n = p0 + ln, t = threadIdx.x;
  const int po = t & 63;
  const int wv = __builtin_amdgcn_readfirstlane(t >> 6);
  const int js = wv >> 1, hf = wv & 1, p = hf * 64 + po;
  const int j0 = js * 16;
  const float* h1p = h1 + (long)ln * 65536;
  float acc[16];
#pragma unroll
  for (int jj = 0; jj < 16; jj++) acc[jj] = 0.f;
  for (int c = 0; c < 8; c++) {
    __syncthreads();
    ((float4*)xbp)[t] = ((const float4*)(h1p + (long)c * 4096))[t];
    ((float4*)xbc)[t] = ((const float4*)(h1p + 32768 + (long)c * 4096))[t];
    ((float4*)wb2)[t] = ((const float4*)(W2P + (long)c * 4096))[t];
    __syncthreads();
    const float* xb = (j0 < 64) ? xbp : xbc;
#pragma unroll 4
    for (int i = 0; i < 32; i++) {
      const float xv = xb[i * 128 + p];
      const float* w = wb2 + i * 128 + j0;
#pragma unroll
      for (int jj = 0; jj < 16; jj++) acc[jj] = fmaf(w[jj], xv, acc[jj]);
    }
  }
#pragma unroll
  for (int jj = 0; jj < 16; jj++) {
    const int j = j0 + jj;
    const float bb = (j < 64) ? p2b[j] : c2b[j - 64];
    h2[j * 128 + p] = fmaxf(acc[jj] + bb, 0.f);
  }
  __syncthreads();

  float sig = 0.f;
  const int pp = t & 127;
  if (t < 128) {
    float o0v = p3b[0], o1v = p3b[1], cv = c3b[0];
    for (int j = 0; j < 64; j++) {
      const float hp = h2[j * 128 + pp];
      const float hc = h2[(64 + j) * 128 + pp];
      o0v = fmaf(p3w[j], hp, o0v);
      o1v = fmaf(p3w[64 + j], hp, o1v);
      cv = fmaf(c3w[j], hc, cv);
    }
    const long ip = ((long)n * 128 + pp) * 2;
    out[ip + 0] = i_it[ip + 0] * 4.f + o0v;
    out[ip + 1] = i_it[ip + 1] * 4.f + o1v;
    out[131072 + (long)n * 128 + pp] = cv;
    sig = 1.f / (1.f + expf(-cv));
  }
  __syncthreads();
  if (t < 128) xbp[pp] = sig;
  __syncthreads();
  if (t < 128) {
    float m = xbp[pp];
#pragma unroll
    for (int s = 1; s <= 2; s++) {
      m = fmaxf(m, xbp[(pp + s) & 127]);
      m = fmaxf(m, xbp[(pp + 128 - s) & 127]);
    }
    out[196608 + (long)n * 128 + pp] = (sig >= m) ? sig : 0.f;
  }
}

extern "C" void kernel_launch(void* const* d_in, const int* in_sizes, int n_in,
                              void* d_out, int out_size, void* d_ws, size_t ws_size,
                              hipStream_t stream) {
  const float* cnn      = (const float*)d_in[0];
  const float* i_it     = (const float*)d_in[1];
  const float* c_it     = (const float*)d_in[2];
  const float* it_cls   = (const float*)d_in[3];
  const int*   ind      = (const int*)d_in[4];
  const float* head_w   = (const float*)d_in[5];
  const float* head_b   = (const float*)d_in[6];
  const float* res_w    = (const float*)d_in[7];
  const float* res_b    = (const float*)d_in[8];
  const float* fusion_w = (const float*)d_in[9];
  const float* fusion_b = (const float*)d_in[10];
  const float* pred1_w  = (const float*)d_in[11];
  const float* pred1_b  = (const float*)d_in[12];
  const float* pred2_w  = (const float*)d_in[13];
  const float* pred2_b  = (const float*)d_in[14];
  const float* pred3_w  = (const float*)d_in[15];
  const float* pred3_b  = (const float*)d_in[16];
  const float* cls1_w   = (const float*)d_in[17];
  const float* cls1_b   = (const float*)d_in[18];
  const float* cls2_w   = (const float*)d_in[19];
  const float* cls2_b   = (const float*)d_in[20];
  const float* cls3_w   = (const float*)d_in[21];
  const float* cls3_b   = (const float*)d_in[22];
  float* ws = (float*)d_ws;
  float* out = (float*)d_out;

  k_repack<<<(int)((REPACK_N + 255) / 256), 256, 0, stream>>>(
      head_w, res_w, fusion_w, pred1_w, cls1_w, pred2_w, cls2_w, ws);

  // chunk polygons by available workspace: per-poly dynamic = 131072 (states) + 65536 (h1) floats
  long avail_f = (long)(ws_size / 4) - OFF_DYN;
  long Cl = avail_f / 196608;
  int C = (int)(Cl < 1 ? 1 : (Cl > 512 ? 512 : Cl));
  float* states = ws + OFF_DYN;
  float* h1 = states + (long)C * 131072;

  for (int p0 = 0; p0 < 512; p0 += C) {
    int Cc = (512 - p0 < C) ? (512 - p0) : C;
    k_conv<<<Cc, 1024, 0, stream>>>(cnn, i_it, c_it, it_cls, ind,
                                    ws + OFF_CWP, ws + OFF_FWF, head_b, res_b,
                                    ws + OFF_GRAW, states, p0);
    k_hg<<<Cc, 512, 0, stream>>>(ws + OFF_GRAW, fusion_b, ws + OFF_W1G,
                                 pred1_b, cls1_b, ws + OFF_HG, p0);
    k_h1<<<2 * Cc, 1024, 0, stream>>>(states, ws + OFF_W1S, ws + OFF_HG, h1, p0);
    k_tail<<<Cc, 1024, 0, stream>>>(h1, ws + OFF_W2P, pred2_b, cls2_b,
                                    pred3_w, pred3_b, cls3_w, cls3_b,
                                    i_it, out, p0);
  }
}

// Round 6
// 3218.948 us; speedup vs baseline: 1.7304x; 1.7304x over previous
//
#include <hip/hip_runtime.h>
#include <math.h>

// ---------------- workspace layout (float offsets) ----------------
#define OFF_CWS  0L         // conv w  [l8][wv16][k9][i128][o8]  = 1179648
#define OFF_FWS  1179648L   // fus  w  [l8][wv16][i128][o16]     = 262144
#define OFF_W1G  1441792L   // W1G  [c256][o512]                 = 131072
#define OFF_W1H  1572864L   // W1H  [ob2][wv16][i1024][o16]      = 524288
#define OFF_W2S  2097152L   // W2S  [wv16][i256][o8]             = 32768
#define OFF_GRAW 2129920L   // graw [512][256]                   = 131072
#define OFF_HG   2260992L   // hg   [512][512]                   = 262144
#define OFF_DYN  2523136L   // dynamic: states [C][1024][128] + h1 [C][512][128]
#define REPACK_N 2129920L

__global__ void k_repack(const float* __restrict__ head_w, const float* __restrict__ res_w,
                         const float* __restrict__ fusion_w,
                         const float* __restrict__ pred1_w, const float* __restrict__ cls1_w,
                         const float* __restrict__ pred2_w, const float* __restrict__ cls2_w,
                         float* __restrict__ ws) {
  long j = (long)blockIdx.x * 256 + threadIdx.x;
  if (j >= REPACK_N) return;
  if (j < OFF_FWS) {                       // CWS[l][wv][k][i][o]
    int o = (int)(j & 7), i = (int)((j >> 3) & 127);
    long q = j >> 10; int k = (int)(q % 9); int wv = (int)((q / 9) & 15); int l = (int)(q / 144);
    int og = wv * 8 + o;
    float v;
    if (l == 0) v = (i < 67) ? head_w[(og * 67 + i) * 9 + k] : 0.f;
    else        v = res_w[(((l - 1) * 128 + og) * 128 + i) * 9 + k];
    ws[j] = v;
  } else if (j < OFF_W1G) {                // FWS[l][wv][i][o]
    long q = j - OFF_FWS;
    int o = (int)(q & 15), i = (int)((q >> 4) & 127), wv = (int)((q >> 11) & 15), l = (int)(q >> 15);
    ws[j] = fusion_w[(long)(wv * 16 + o) * 1024 + l * 128 + i];
  } else if (j < OFF_W1H) {                // W1G[c][o]
    long q = j - OFF_W1G; int o = (int)(q & 511); int c = (int)(q >> 9);
    ws[j] = (o < 256) ? pred1_w[(long)o * 1280 + c] : cls1_w[(long)(o - 256) * 1280 + c];
  } else if (j < OFF_W2S) {                // W1H[ob][wv][i][o]
    long q = j - OFF_W1H;
    int o = (int)(q & 15), i = (int)((q >> 4) & 1023), wv = (int)((q >> 14) & 15), ob = (int)(q >> 18);
    int ho = ob * 256 + wv * 16 + o, c = 256 + i;
    ws[j] = (ho < 256) ? pred1_w[(long)ho * 1280 + c] : cls1_w[(long)(ho - 256) * 1280 + c];
  } else if (j < OFF_GRAW) {               // W2S[wv][i][o]
    long q = j - OFF_W2S;
    int o = (int)(q & 7), i = (int)((q >> 3) & 255), wv = (int)(q >> 11);
    int jg = wv * 8 + o;
    ws[j] = (jg < 64) ? pred2_w[jg * 256 + i] : cls2_w[(jg - 64) * 256 + i];
  }
}

// =============== K1: gather + 8-layer conv chain + incremental fus + states write ===============
// Weights are read with wave-uniform addresses -> backend scalarizes to s_load (SGPR operand FMAs).
__global__ __launch_bounds__(1024) __attribute__((amdgpu_waves_per_eu(4)))
void k_conv(const float* __restrict__ cnn, const float* __restrict__ i_it,
            const float* __restrict__ c_it, const float* __restrict__ cls_in,
            const int* __restrict__ ind,
            const float* __restrict__ CWS, const float* __restrict__ FWS,
            const float* __restrict__ head_b, const float* __restrict__ res_b,
            float* __restrict__ graw, float* __restrict__ states, int p0) {
  __shared__ float sx[16384];    // [128 ch][128 pos] 64 KB
  const int ln = blockIdx.x, n = p0 + ln, t = threadIdx.x;
  const int po = t & 63;
  const int wv = __builtin_amdgcn_readfirstlane(t >> 6);
  const int ob = wv * 8;

  // ---- bilinear gather ----
  {
    const int p4 = t & 127, og4 = t >> 7;
    const float gx = i_it[((long)n * 128 + p4) * 2 + 0] - 0.5f;
    const float gy = i_it[((long)n * 128 + p4) * 2 + 1] - 0.5f;
    const float fx = floorf(gx), fy = floorf(gy);
    const float wx = gx - fx, wy = gy - fy;
    const int x0 = (int)fx, y0 = (int)fy, x1 = x0 + 1, y1 = y0 + 1;
    const bool vx0 = (x0 >= 0) & (x0 < 128), vx1 = (x1 >= 0) & (x1 < 128);
    const bool vy0 = (y0 >= 0) & (y0 < 128), vy1 = (y1 >= 0) & (y1 < 128);
    const int x0c = min(max(x0, 0), 127), x1c = min(max(x1, 0), 127);
    const int y0c = min(max(y0, 0), 127), y1c = min(max(y1, 0), 127);
    const float w00 = (vx0 && vy0) ? (1.f - wx) * (1.f - wy) : 0.f;
    const float w01 = (vx1 && vy0) ? wx * (1.f - wy) : 0.f;
    const float w10 = (vx0 && vy1) ? (1.f - wx) * wy : 0.f;
    const float w11 = (vx1 && vy1) ? wx * wy : 0.f;
    const long base = (long)ind[n] * 64 * 16384;
    const int a00 = y0c * 128 + x0c, a01 = y0c * 128 + x1c;
    const int a10 = y1c * 128 + x0c, a11 = y1c * 128 + x1c;
    for (int cc = 0; cc < 8; cc++) {
      const int c = og4 * 8 + cc;
      const float* f = cnn + base + (long)c * 16384;
      sx[c * 128 + p4] = f[a00] * w00 + f[a01] * w01 + f[a10] * w10 + f[a11] * w11;
    }
    if (og4 == 0) {
      sx[64 * 128 + p4] = c_it[((long)n * 128 + p4) * 2 + 0] * 4.0f;
      sx[65 * 128 + p4] = c_it[((long)n * 128 + p4) * 2 + 1] * 4.0f;
      sx[66 * 128 + p4] = cls_in[(long)n * 128 + p4];
    }
  }
  for (int idx = t; idx < 61 * 128; idx += 1024) sx[67 * 128 + idx] = 0.f;
  __syncthreads();

  float f0[16], f1[16];
#pragma unroll
  for (int r = 0; r < 16; r++) { f0[r] = 0.f; f1[r] = 0.f; }
  float* st = states + (long)ln * 131072;

  for (int l = 0; l < 8; l++) {
    const int dil = (l >= 6) ? 4 : ((l >= 4) ? 2 : 1);
    const int ni = (l == 0) ? 68 : 128;    // head conv: rows >=67 are zero (weights+data)
    float a0[8], a1[8];
    {
      const float* bsrc = (l == 0) ? (head_b + ob) : (res_b + (l - 1) * 128 + ob);
#pragma unroll
      for (int oo = 0; oo < 8; oo++) { a0[oo] = bsrc[oo]; a1[oo] = a0[oo]; }
    }
    const float* wl = CWS + (long)(l * 16 + wv) * 9216;
    for (int k = 0; k < 9; k++) {
      const int xa0 = (po + (k - 4) * dil + 128) & 127;
      const int xa1 = xa0 ^ 64;
      const float* wk = wl + k * 1024;
#pragma unroll 4
      for (int i = 0; i < ni; i++) {
        const float xv0 = sx[i * 128 + xa0];
        const float xv1 = sx[i * 128 + xa1];
        const float* w = wk + i * 8;       // wave-uniform -> s_load
#pragma unroll
        for (int oo = 0; oo < 8; oo++) {
          a0[oo] = fmaf(w[oo], xv0, a0[oo]);
          a1[oo] = fmaf(w[oo], xv1, a1[oo]);
        }
      }
    }
    __syncthreads();
#pragma unroll
    for (int oo = 0; oo < 8; oo++) {
      const int o = ob + oo;
      float v0 = fmaxf(a0[oo], 0.f), v1 = fmaxf(a1[oo], 0.f);
      if (l > 0) { v0 += sx[o * 128 + po]; v1 += sx[o * 128 + po + 64]; }
      sx[o * 128 + po] = v0;
      sx[o * 128 + po + 64] = v1;
      st[(l * 128 + o) * 128 + po] = v0;
      st[(l * 128 + o) * 128 + po + 64] = v1;
    }
    __syncthreads();

    // ---- incremental fusion for slot l (weights via s_load) ----
    const float* fl = FWS + (long)(l * 16 + wv) * 2048;
#pragma unroll 2
    for (int i = 0; i < 128; i++) {
      const float xv0 = sx[i * 128 + po];
      const float xv1 = sx[i * 128 + po + 64];
      const float* w = fl + i * 16;        // wave-uniform -> s_load
#pragma unroll
      for (int r = 0; r < 16; r++) {
        f0[r] = fmaf(w[r], xv0, f0[r]);
        f1[r] = fmaf(w[r], xv1, f1[r]);
      }
    }
  }

  // ---- fusion max over all 128 positions -> graw ----
#pragma unroll
  for (int r = 0; r < 16; r++) {
    float m = fmaxf(f0[r], f1[r]);
#pragma unroll
    for (int s = 32; s > 0; s >>= 1) m = fmaxf(m, __shfl_xor(m, s, 64));
    if (po == 0) graw[(long)n * 256 + wv * 16 + r] = m;
  }
}

// =============== K_hg: hg[n][o] = bias + W1G[:,o].(graw+fus_b) ===============
__global__ __launch_bounds__(512)
void k_hg(const float* __restrict__ graw, const float* __restrict__ fus_b,
          const float* __restrict__ W1G, const float* __restrict__ p1b, const float* __restrict__ c1b,
          float* __restrict__ hg, int p0) {
  __shared__ float sg[256];
  const int n = p0 + blockIdx.x, t = threadIdx.x;
  if (t < 256) sg[t] = graw[(long)n * 256 + t] + fus_b[t];
  __syncthreads();
  float s = (t < 256) ? p1b[t] : c1b[t - 256];
  const float* w = W1G + t;
#pragma unroll 8
  for (int c = 0; c < 256; c++) s = fmaf(w[(long)c * 512], sg[c], s);
  hg[(long)n * 512 + t] = s;
}

// =============== K2: h1 = relu(W1H @ states + hg), 2 blocks/poly ===============
__global__ __launch_bounds__(1024) __attribute__((amdgpu_waves_per_eu(4)))
void k_h1(const float* __restrict__ states, const float* __restrict__ W1H,
          const float* __restrict__ hg, float* __restrict__ h1, int p0) {
  __shared__ float xb[2][2048];
  const int b = blockIdx.x, ln = b >> 1, obh = b & 1;
  const int t = threadIdx.x, po = t & 63;
  const int wv = __builtin_amdgcn_readfirstlane(t >> 6);
  const float* xs = states + (long)ln * 131072;
  const float* wbase = W1H + (long)(obh * 16 + wv) * 16384;
  float a0[16], a1[16];
#pragma unroll
  for (int oo = 0; oo < 16; oo++) { a0[oo] = 0.f; a1[oo] = 0.f; }

  float2 px = ((const float2*)xs)[t];
  int buf = 0;
  for (int c = 0; c < 64; c++) {
    ((float2*)xb[buf])[t] = px;
    __syncthreads();
    if (c + 1 < 64) px = ((const float2*)(xs + (long)(c + 1) * 2048))[t];
    const float* xp = xb[buf];
    const float* wc = wbase + c * 256;
#pragma unroll 4
    for (int i = 0; i < 16; i++) {
      const float xv0 = xp[i * 128 + po];
      const float xv1 = xp[i * 128 + po + 64];
      const float* w = wc + i * 16;        // wave-uniform -> s_load
#pragma unroll
      for (int oo = 0; oo < 16; oo++) {
        a0[oo] = fmaf(w[oo], xv0, a0[oo]);
        a1[oo] = fmaf(w[oo], xv1, a1[oo]);
      }
    }
    __syncthreads();
    buf ^= 1;
  }
  const int n = p0 + ln;
  const int row0 = obh * 256 + wv * 16;
  const float* hgp = hg + (long)n * 512 + row0;
  float* dst = h1 + (long)ln * 65536 + (long)row0 * 128;
#pragma unroll
  for (int oo = 0; oo < 16; oo++) {
    const float bb = hgp[oo];
    dst[oo * 128 + po] = fmaxf(a0[oo] + bb, 0.f);
    dst[oo * 128 + po + 64] = fmaxf(a1[oo] + bb, 0.f);
  }
}

// =============== K3: pred2/cls2 + pred3/cls3 + outputs + NMS ===============
__global__ __launch_bounds__(1024) __attribute__((amdgpu_waves_per_eu(4)))
void k_tail(const float* __restrict__ h1, const float* __restrict__ W2S,
            const float* __restrict__ p2b, const float* __restrict__ c2b,
            const float* __restrict__ p3w, const float* __restrict__ p3b,
            const float* __restrict__ c3w, const float* __restrict__ c3b,
            const float* __restrict__ i_it, float* __restrict__ out, int p0) {
  __shared__ float h2[16384];
  __shared__ float xb[2048], xc[2048];
  const int ln = blockIdx.x, n = p0 + ln, t = threadIdx.x;
  const int po = t & 63;
  const int wv = __builtin_amdgcn_readfirstlane(t >> 6);
  const float* h1p = h1 + (long)ln * 65536;
  const float* wbase = W2S + (long)wv * 2048;
  float a0[8], a1[8];
#pragma unroll
  for (int jj = 0; jj < 8; jj++) { a0[jj] = 0.f; a1[jj] = 0.f; }
  for (int c = 0; c < 16; c++) {
    __syncthreads();
    ((float2*)xb)[t] = ((const float2*)(h1p + (long)c * 2048))[t];
    ((float2*)xc)[t] = ((const float2*)(h1p + 32768 + (long)c * 2048))[t];
    __syncthreads();
    const float* xp = (wv < 8) ? xb : xc;
    const float* wc = wbase + c * 128;
#pragma unroll 4
    for (int i = 0; i < 16; i++) {
      const float xv0 = xp[i * 128 + po];
      const float xv1 = xp[i * 128 + po + 64];
      const float* w = wc + i * 8;         // wave-uniform -> s_load
#pragma unroll
      for (int jj = 0; jj < 8; jj++) {
        a0[jj] = fmaf(w[jj], xv0, a0[jj]);
        a1[jj] = fmaf(w[jj], xv1, a1[jj]);
      }
    }
  }
#pragma unroll
  for (int jj = 0; jj < 8; jj++) {
    const int j = wv * 8 + jj;
    const float bb = (j < 64) ? p2b[j] : c2b[j - 64];
    h2[j * 128 + po] = fmaxf(a0[jj] + bb, 0.f);
    h2[j * 128 + po + 64] = fmaxf(a1[jj] + bb, 0.f);
  }
  __syncthreads();

  float sig = 0.f;
  const int pp = t & 127;
  if (t < 128) {
    float o0v = p3b[0], o1v = p3b[1], cv = c3b[0];
    for (int j = 0; j < 64; j++) {
      const float hp = h2[j * 128 + pp];
      const float hc = h2[(64 + j) * 128 + pp];
      o0v = fmaf(p3w[j], hp, o0v);
      o1v = fmaf(p3w[64 + j], hp, o1v);
      cv = fmaf(c3w[j], hc, cv);
    }
    const long ip = ((long)n * 128 + pp) * 2;
    out[ip + 0] = i_it[ip + 0] * 4.f + o0v;
    out[ip + 1] = i_it[ip + 1] * 4.f + o1v;
    out[131072 + (long)n * 128 + pp] = cv;
    sig = 1.f / (1.f + expf(-cv));
  }
  __syncthreads();
  if (t < 128) xb[pp] = sig;
  __syncthreads();
  if (t < 128) {
    float m = xb[pp];
#pragma unroll
    for (int s = 1; s <= 2; s++) {
      m = fmaxf(m, xb[(pp + s) & 127]);
      m = fmaxf(m, xb[(pp + 128 - s) & 127]);
    }
    out[196608 + (long)n * 128 + pp] = (sig >= m) ? sig : 0.f;
  }
}

extern "C" void kernel_launch(void* const* d_in, const int* in_sizes, int n_in,
                              void* d_out, int out_size, void* d_ws, size_t ws_size,
                              hipStream_t stream) {
  const float* cnn      = (const float*)d_in[0];
  const float* i_it     = (const float*)d_in[1];
  const float* c_it     = (const float*)d_in[2];
  const float* it_cls   = (const float*)d_in[3];
  const int*   ind      = (const int*)d_in[4];
  const float* head_w   = (const float*)d_in[5];
  const float* head_b   = (const float*)d_in[6];
  const float* res_w    = (const float*)d_in[7];
  const float* res_b    = (const float*)d_in[8];
  const float* fusion_w = (const float*)d_in[9];
  const float* fusion_b = (const float*)d_in[10];
  const float* pred1_w  = (const float*)d_in[11];
  const float* pred1_b  = (const float*)d_in[12];
  const float* pred2_w  = (const float*)d_in[13];
  const float* pred2_b  = (const float*)d_in[14];
  const float* pred3_w  = (const float*)d_in[15];
  const float* pred3_b  = (const float*)d_in[16];
  const float* cls1_w   = (const float*)d_in[17];
  const float* cls1_b   = (const float*)d_in[18];
  const float* cls2_w   = (const float*)d_in[19];
  const float* cls2_b   = (const float*)d_in[20];
  const float* cls3_w   = (const float*)d_in[21];
  const float* cls3_b   = (const float*)d_in[22];
  float* ws = (float*)d_ws;
  float* out = (float*)d_out;

  k_repack<<<(int)((REPACK_N + 255) / 256), 256, 0, stream>>>(
      head_w, res_w, fusion_w, pred1_w, cls1_w, pred2_w, cls2_w, ws);

  // chunk polygons; clamp to multiples of 256 CUs for balanced rounds
  long avail_f = (long)(ws_size / 4) - OFF_DYN;
  long Cl = avail_f / 196608;
  int C = (Cl >= 512) ? 512 : ((Cl >= 256) ? 256 : (int)(Cl < 1 ? 1 : Cl));
  float* states = ws + OFF_DYN;
  float* h1 = states + (long)C * 131072;

  for (int p0 = 0; p0 < 512; p0 += C) {
    int Cc = (512 - p0 < C) ? (512 - p0) : C;
    k_conv<<<Cc, 1024, 0, stream>>>(cnn, i_it, c_it, it_cls, ind,
                                    ws + OFF_CWS, ws + OFF_FWS, head_b, res_b,
                                    ws + OFF_GRAW, states, p0);
    k_hg<<<Cc, 512, 0, stream>>>(ws + OFF_GRAW, fusion_b, ws + OFF_W1G,
                                 pred1_b, cls1_b, ws + OFF_HG, p0);
    k_h1<<<2 * Cc, 1024, 0, stream>>>(states, ws + OFF_W1H, ws + OFF_HG, h1, p0);
    k_tail<<<Cc, 1024, 0, stream>>>(h1, ws + OFF_W2S, pred2_b, cls2_b,
                                    pred3_w, pred3_b, cls3_w, cls3_b,
                                    i_it, out, p0);
  }
}